// Round 15
// baseline (5534.451 us; speedup 1.0000x reference)
//
#include <hip/hip_runtime.h>
#include <hip/hip_bf16.h>
#include <cstdint>
#include <cstddef>

#define B_   64
#define T_   512
#define D_   512
#define H0_  1024
#define H1_  512
#define NGRP 4
#define BPG  64
#define NWORK 256
#define WPB  6      // waves per block (384 threads)

typedef __attribute__((ext_vector_type(8))) short bf16x8;
typedef __attribute__((ext_vector_type(4))) float f32x4;
typedef unsigned long long u64;

// LDS: per-wave frag regions 6x16KB | zw 6x1280 | pack 6x512 | phase flag
#define FR_OFF  0
#define ZW_OFF  98304
#define PK_OFF  105984
#define PF_OFF  109056
#define LDS_BYTES 110592

__device__ __forceinline__ float sigmf(float x) { return 1.0f / (1.0f + __expf(-x)); }
__device__ __forceinline__ unsigned short bf16bits(float x) {
    union { __hip_bfloat16 h; unsigned short s; } u; u.h = __float2bfloat16(x); return u.s;
}
__device__ __forceinline__ u64 ald(const void* p) {
    return __hip_atomic_load((const u64*)p, __ATOMIC_RELAXED, __HIP_MEMORY_SCOPE_AGENT);
}

// ---------------------------------------------------------------------------
__global__ void mask_kernel(const float* __restrict__ x, unsigned char* __restrict__ mask) {
    int row  = blockIdx.x * 4 + (threadIdx.x >> 6);
    int lane = threadIdx.x & 63;
    const float4* p = reinterpret_cast<const float4*>(x + (size_t)row * D_) + lane * 2;
    float4 a = p[0], b = p[1];
    bool nz = (a.x != 0.f) | (a.y != 0.f) | (a.z != 0.f) | (a.w != 0.f)
            | (b.x != 0.f) | (b.y != 0.f) | (b.z != 0.f) | (b.w != 0.f);
    int m = __any(nz);
    if (lane == 0) mask[row] = m ? 1 : 0;
}

__global__ void xbf_kernel(const float* __restrict__ in, __hip_bfloat16* __restrict__ xbf) {
    int i  = blockIdx.x * 256 + threadIdx.x;
    int d8 = i & 63;
    int row = i >> 6;
    int b = row >> 9, t = row & 511;
    const float* src = in + (size_t)row * D_ + d8 * 8;
    __hip_bfloat16 o[8];
    #pragma unroll
    for (int j = 0; j < 8; ++j) o[j] = __float2bfloat16(src[j]);
    *reinterpret_cast<bf16x8*>(xbf + ((size_t)t * B_ + b) * D_ + d8 * 8) =
        *reinterpret_cast<bf16x8*>(o);
}

// ---------------------------------------------------------------------------
// Full-K-per-wave persistent LSTM. 4 groups x 16 batches; 64 blocks/group;
// 6 waves/block. Wave w<4: z0 for units ub0+w*4..+3 (cols u*4+g, full K=1536:
// 16 x-chunks from LDS frags [PRE] + 32 h0-chunks from VGPR frags).
// Wave w>=4: z1 for units ub1+(w-4)*4..+3 (16 h1-chunks LDS + 32 h0 VGPR).
// NO __syncthreads in the phase loop: gates via wave-local LDS transpose;
// wave0 polls global flags + acquire fence + LDS phase-flag release;
// waves 1-5 spin on LDS. Arrive: per-wave vmcnt(0) + own global flag.
// h stores sc0sc1 (LLC write-through); h reads plain cached (L2-amplified).
// ---------------------------------------------------------------------------
__global__ __launch_bounds__(384, 1)
void lstm_persistent(const __hip_bfloat16* __restrict__ xbf,
    const float* __restrict__ W0, const float* __restrict__ U0,
    const float* __restrict__ W1, const float* __restrict__ U1,
    const float* __restrict__ b0, const float* __restrict__ b1,
    const unsigned char* __restrict__ mask,
    __hip_bfloat16* h0ring, __hip_bfloat16* h1ring, float* __restrict__ out,
    int* flags)
{
    __shared__ __align__(16) unsigned char smem[LDS_BYTES];
    const int bid = blockIdx.x;
    const int g   = bid >> 6;          // group (0..3)
    const int lb  = bid & 63;          // block within group
    const int tid = threadIdx.x;
    const int w = tid >> 6, lane = tid & 63;
    const int mr = lane & 15, kgrp = lane >> 4;
    const int ub0 = lb * 16, ub1 = lb * 8;
    const int brow = g * 16;
    int* gfl = flags + g * (BPG * WPB);
    volatile int* pf = (volatile int*)(smem + PF_OFF);

    // ---- weight fragment column for this lane: nn = lane&15 = u*4 + gate
    const int uf  = (lane & 15) >> 2;
    const int gtf = lane & 3;

    __hip_bfloat16* lfr = (__hip_bfloat16*)(smem + FR_OFF + w * 16384);
    bf16x8 bwt[32];   // full-K h0-chunk weight frags (U0 or W1), VGPR-resident

    if (w < 4) {
        const int colw = gtf * 1024 + ub0 + w * 4 + uf;   // L0 gate-major col
        // LDS: W0 x-chunks (cid 0..15)
        #pragma unroll 4
        for (int c = 0; c < 16; ++c) {
            __hip_bfloat16* dst = lfr + ((size_t)c * 64 + lane) * 8;
            #pragma unroll
            for (int j = 0; j < 8; ++j)
                dst[j] = __float2bfloat16(W0[(size_t)(c * 32 + kgrp * 8 + j) * 4096 + colw]);
        }
        // VGPR: U0 h0-chunks (cid 0..31)
        #pragma unroll
        for (int c = 0; c < 32; ++c) {
            union { short s[8]; bf16x8 v; } t;
            #pragma unroll
            for (int j = 0; j < 8; ++j)
                t.s[j] = (short)bf16bits(U0[(size_t)(c * 32 + kgrp * 8 + j) * 4096 + colw]);
            bwt[c] = t.v;
        }
    } else {
        const int colw = gtf * 512 + ub1 + (w - 4) * 4 + uf; // L1 gate-major col
        // LDS: U1 h1-chunks (cid 0..15)
        #pragma unroll 4
        for (int c = 0; c < 16; ++c) {
            __hip_bfloat16* dst = lfr + ((size_t)c * 64 + lane) * 8;
            #pragma unroll
            for (int j = 0; j < 8; ++j)
                dst[j] = __float2bfloat16(U1[(size_t)(c * 32 + kgrp * 8 + j) * 2048 + colw]);
        }
        // VGPR: W1 h0-chunks (cid 0..31)
        #pragma unroll
        for (int c = 0; c < 32; ++c) {
            union { short s[8]; bf16x8 v; } t;
            #pragma unroll
            for (int j = 0; j < 8; ++j)
                t.s[j] = (short)bf16bits(W1[(size_t)(c * 32 + kgrp * 8 + j) * 2048 + colw]);
            bwt[c] = t.v;
        }
    }

    // ---- per-lane gate state: lane -> (batch = lane>>2, unit = lane&3)
    float br[4];
    if (w < 4) {
        #pragma unroll
        for (int gt = 0; gt < 4; ++gt)
            br[gt] = b0[gt * H0_ + ub0 + w * 4 + (lane & 3)];
    } else {
        #pragma unroll
        for (int gt = 0; gt < 4; ++gt)
            br[gt] = b1[gt * H1_ + ub1 + (w - 4) * 4 + (lane & 3)];
    }
    float creg = 0.f, hreg = 0.f;

    if (tid == 0) *pf = 0;
    __syncthreads();   // only barrier: LDS frags + phase flag init

    float* zwf = (float*)(smem + ZW_OFF + w * 1280);
    unsigned short* hpk = (unsigned short*)(smem + PK_OFF + w * 512);
    float* opk = (float*)(smem + PK_OFF + w * 512 + 128);
    const bf16x8* frv = (const bf16x8*)lfr;

    #pragma unroll 1
    for (int p = 0; p <= T_; ++p) {
        const bool act0 = (w < 4) && (p < T_);
        const bool act1 = (w >= 4) && (p >= 1);

        f32x4 acc = {0.f, 0.f, 0.f, 0.f};

        // ---- prefetch mask (pre-wait, L2)
        bool mk = false;
        if (act0) mk = mask[(brow + (lane >> 2)) * T_ + p] != 0;
        if (act1) mk = mask[(brow + (lane >> 2)) * T_ + (p - 1)] != 0;

        // ---- PRE (z0): x chunks, LDS W0 frags — overlaps the wait
        if (act0) {
            const __hip_bfloat16* xa = xbf + (size_t)p * (B_ * D_)
                                     + (size_t)(brow + mr) * D_ + kgrp * 8;
            #pragma unroll
            for (int c = 0; c < 16; ++c) {
                bf16x8 af = *(const bf16x8*)(xa + c * 32);
                acc = __builtin_amdgcn_mfma_f32_16x16x32_bf16(af, frv[c * 64 + lane], acc, 0, 0, 0);
            }
        }

        // ---- wait: wave0 polls 384 group flags, fences, releases LDS flag
        if (p > 0) {
            if (w == 0) {
                const u64* f = (const u64*)gfl;
                for (;;) {
                    u64 a = ald(f + lane);
                    u64 b = ald(f + lane + 64);
                    u64 c = ald(f + lane + 128);
                    bool ok = ((int)a >= p) && ((int)(a >> 32) >= p)
                           && ((int)b >= p) && ((int)(b >> 32) >= p)
                           && ((int)c >= p) && ((int)(c >> 32) >= p);
                    if (__all(ok)) break;
                    __builtin_amdgcn_s_sleep(1);
                }
                __builtin_amdgcn_fence(__ATOMIC_ACQUIRE, "agent");
                __hip_atomic_store((int*)pf, p, __ATOMIC_RELEASE, __HIP_MEMORY_SCOPE_WORKGROUP);
            } else {
                while (__hip_atomic_load((int*)pf, __ATOMIC_ACQUIRE, __HIP_MEMORY_SCOPE_WORKGROUP) < p)
                    __builtin_amdgcn_s_sleep(1);
            }
        }

        const __hip_bfloat16* h0r = h0ring + (size_t)((p + 1) & 1) * (B_ * H0_); // h0(p-1)
        const __hip_bfloat16* h1r = h1ring + (size_t)(p & 1) * (B_ * H1_);       // h1(p-2)

        // ---- MAIN MFMA chains (plain cached loads, L2-amplified)
        if (act1) {
            const __hip_bfloat16* h1a = h1r + (size_t)(brow + mr) * H1_ + kgrp * 8;
            #pragma unroll
            for (int c = 0; c < 16; ++c) {
                bf16x8 af = *(const bf16x8*)(h1a + c * 32);
                acc = __builtin_amdgcn_mfma_f32_16x16x32_bf16(af, frv[c * 64 + lane], acc, 0, 0, 0);
            }
        }
        if (act0 || act1) {
            const __hip_bfloat16* h0a = h0r + (size_t)(brow + mr) * H0_ + kgrp * 8;
            bf16x8 areg[4];
            #pragma unroll
            for (int c = 0; c < 4; ++c) areg[c] = *(const bf16x8*)(h0a + c * 32);
            #pragma unroll
            for (int c = 0; c < 32; ++c) {
                bf16x8 cur = areg[c & 3];
                if (c + 4 < 32) areg[c & 3] = *(const bf16x8*)(h0a + (c + 4) * 32);
                acc = __builtin_amdgcn_mfma_f32_16x16x32_bf16(cur, bwt[c], acc, 0, 0, 0);
            }
        }

        // ---- gates: wave-local LDS transpose (no barrier), per-lane (b,u)
        if (act0 || act1) {
            #pragma unroll
            for (int r = 0; r < 4; ++r)
                zwf[(kgrp * 4 + r) * 20 + mr] = acc[r];
            f32x4 zv = *(f32x4*)(zwf + (lane >> 2) * 20 + (lane & 3) * 4);
            float zi = zv[0] + br[0], zf = zv[1] + br[1];
            float zg = zv[2] + br[2], zo = zv[3] + br[3];
            float ig = sigmf(zi), fg = sigmf(zf);
            float gv = tanhf(zg), og = sigmf(zo);
            float cn = fg * creg + ig * gv;
            float hn = og * tanhf(cn);
            if (mk) { creg = cn; hreg = hn; }

            hpk[lane] = bf16bits(hreg);
            if (act1) opk[lane] = hreg;
            if (lane < 16) {
                u64 hv = *(const u64*)(hpk + lane * 4);
                if (act0) {
                    __hip_bfloat16* h0w = h0ring + (size_t)(p & 1) * (B_ * H0_);
                    __hip_atomic_store((u64*)(h0w + (size_t)(brow + lane) * H0_ + ub0 + w * 4),
                                       hv, __ATOMIC_RELAXED, __HIP_MEMORY_SCOPE_AGENT);
                } else {
                    __hip_bfloat16* h1w = h1ring + (size_t)((p + 1) & 1) * (B_ * H1_); // slot (p-1)&1
                    __hip_atomic_store((u64*)(h1w + (size_t)(brow + lane) * H1_ + ub1 + (w - 4) * 4),
                                       hv, __ATOMIC_RELAXED, __HIP_MEMORY_SCOPE_AGENT);
                }
            }
        }

        // ---- per-wave arrive: drain own stores, publish own flag
        if (p < T_) {
            asm volatile("s_waitcnt vmcnt(0)" ::: "memory");
            if (lane == 0)
                __hip_atomic_store(gfl + lb * WPB + w, p + 1,
                                   __ATOMIC_RELAXED, __HIP_MEMORY_SCOPE_AGENT);
        }

        // ---- out store after flag (off critical path)
        if (act1 && lane < 16) {
            f32x4 ov = *(f32x4*)(opk + lane * 4);
            *(f32x4*)(out + ((size_t)(brow + lane) * T_ + (p - 1)) * H1_ + ub1 + (w - 4) * 4) = ov;
        }
    }
}

// ---------------------------------------------------------------------------
extern "C" void kernel_launch(void* const* d_in, const int* in_sizes, int n_in,
                              void* d_out, int out_size, void* d_ws, size_t ws_size,
                              hipStream_t stream)
{
    const float* inputs = (const float*)d_in[0];
    const float* W0     = (const float*)d_in[1];
    const float* U0     = (const float*)d_in[2];
    const float* b0     = (const float*)d_in[3];
    const float* W1     = (const float*)d_in[4];
    const float* U1     = (const float*)d_in[5];
    const float* b1     = (const float*)d_in[6];
    float* out = (float*)d_out;

    // ws (bf16 elems): xbf 16,777,216 | h0ring 131,072 | h1ring 65,536
    //                  | mask 32,768 B | flags 6,144 B  (~33.7 MB)
    __hip_bfloat16* xbf    = (__hip_bfloat16*)d_ws;
    __hip_bfloat16* h0ring = xbf + 16777216;
    __hip_bfloat16* h1ring = h0ring + 131072;
    unsigned char*  mask   = (unsigned char*)(h1ring + 65536);
    int* flags = (int*)(mask + 32768);

    hipMemsetAsync(h0ring, 0, (131072 + 65536) * sizeof(__hip_bfloat16), stream);
    hipMemsetAsync(flags, 0, NGRP * BPG * WPB * sizeof(int), stream);
    mask_kernel<<<(B_ * T_) / 4, 256, 0, stream>>>(inputs, mask);
    xbf_kernel<<<(B_ * T_ * D_ / 8) / 256, 256, 0, stream>>>(inputs, xbf);

    lstm_persistent<<<dim3(NWORK), dim3(384), 0, stream>>>(
        xbf, W0, U0, W1, U1, b0, b1, mask, h0ring, h1ring, out, flags);
}

// Round 16
// 4942.861 us; speedup vs baseline: 1.1197x; 1.1197x over previous
//
#include <hip/hip_runtime.h>
#include <hip/hip_bf16.h>
#include <cstdint>
#include <cstddef>

#define B_   64
#define T_   512
#define D_   512
#define H0_  1024
#define H1_  512
#define NWORK 256    // 2 groups x 128 blocks, 1 block/CU, plain launch

typedef __attribute__((ext_vector_type(8))) short bf16x8;
typedef __attribute__((ext_vector_type(4))) float f32x4;
typedef unsigned long long u64;

// LDS: U0 64KB @0 | W1 32KB @65536 | zp0 18,432B @98304 | zp1 10,240B @116736
#define LDS_U0  0
#define LDS_W1  65536
#define LDS_ZP0 98304
#define LDS_ZP1 116736
#define LDS_BYTES 126976
#define ZROW0 36
#define ZROW1 20

__device__ __forceinline__ float sigmf(float x) { return 1.0f / (1.0f + __expf(-x)); }
__device__ __forceinline__ unsigned short bf16bits(float x) {
    union { __hip_bfloat16 h; unsigned short s; } u; u.h = __float2bfloat16(x); return u.s;
}
__device__ __forceinline__ u64 ald(const void* p) {
    return __hip_atomic_load((const u64*)p, __ATOMIC_RELAXED, __HIP_MEMORY_SCOPE_AGENT);
}

// ---------------------------------------------------------------------------
__global__ void mask_kernel(const float* __restrict__ x, unsigned char* __restrict__ mask) {
    int row  = blockIdx.x * 4 + (threadIdx.x >> 6);
    int lane = threadIdx.x & 63;
    const float4* p = reinterpret_cast<const float4*>(x + (size_t)row * D_) + lane * 2;
    float4 a = p[0], b = p[1];
    bool nz = (a.x != 0.f) | (a.y != 0.f) | (a.z != 0.f) | (a.w != 0.f)
            | (b.x != 0.f) | (b.y != 0.f) | (b.z != 0.f) | (b.w != 0.f);
    int m = __any(nz);
    if (lane == 0) mask[row] = m ? 1 : 0;
}

__global__ void xbf_kernel(const float* __restrict__ in, __hip_bfloat16* __restrict__ xbf) {
    int i  = blockIdx.x * 256 + threadIdx.x;
    int d8 = i & 63;
    int row = i >> 6;
    int b = row >> 9, t = row & 511;
    const float* src = in + (size_t)row * D_ + d8 * 8;
    __hip_bfloat16 o[8];
    #pragma unroll
    for (int j = 0; j < 8; ++j) o[j] = __float2bfloat16(src[j]);
    *reinterpret_cast<bf16x8*>(xbf + ((size_t)t * B_ + b) * D_ + d8 * 8) =
        *reinterpret_cast<bf16x8*>(o);
}

// ---------------------------------------------------------------------------
// R13 base + L1 lag-2 + parallel gates.
// Phase p: L0 computes t=p; L1 computes t1=p-2.
//   PRE (pre-wait): mask loads; x_p*W0 (reg frags) -> acc0;
//                   W1*h0(p-2) (LDS frags; slot (p+2)&3, L2-warm) -> acc1.
//   wait: wave0 polls 128 block-flags, acquire fence (inv), barrier.
//   POST: h1(p-3) loads (slot (p+1)&1) -> U1 (reg frags) -> acc1;
//         h0(p-1) 4-deep pipeline (slot (p+3)&3) -> U0 -> acc0;
//         dumps -> sync -> gates0 (qp<4) PARALLEL gates1 (qp 4..5) -> h stores
//         -> sync -> tid0 flag -> out(t1) store.
// h0 ring = 4 slots (WAR with lag-2 reader verified); h1 ring = 2 slots
// (write slot p&1 = h1(p-2), read slot (p+1)&1 = h1(p-3)).
// h writes sc0sc1 (LLC write-through); h reads plain cached (L2-amplified,
// coherence via per-phase leader acquire fence) — both R13-proven.
// ---------------------------------------------------------------------------
__global__ __launch_bounds__(256, 1)
void lstm_persistent(const __hip_bfloat16* __restrict__ xbf,
    const float* __restrict__ W0, const float* __restrict__ U0,
    const float* __restrict__ W1, const float* __restrict__ U1,
    const float* __restrict__ b0, const float* __restrict__ b1,
    const unsigned char* __restrict__ mask,
    __hip_bfloat16* h0ring, __hip_bfloat16* h1ring, float* __restrict__ out,
    int* flags)
{
    __shared__ __align__(16) unsigned char smem[LDS_BYTES];
    const int bid = blockIdx.x;
    const int g   = bid >> 7;          // batch group (0/1)
    const int lb  = bid & 127;         // block within group
    const int tid = threadIdx.x;
    const int w = tid >> 6, lane = tid & 63;
    const int mr = lane & 15, kgrp = lane >> 4;
    const int ub0 = lb * 8, ub1 = lb * 4;
    const int brow = g * 32;           // batch row base
    int* gflags = flags + g * 128;

    __hip_bfloat16* lu0h = (__hip_bfloat16*)(smem + LDS_U0);
    __hip_bfloat16* lw1h = (__hip_bfloat16*)(smem + LDS_W1);

    // ---- one-time LDS fill: U0 frags (cid 0..31, nf 0..1)
    for (int e = tid; e < 32 * 2 * 64; e += 256) {
        int ln  = e & 63;
        int nf  = (e >> 6) & 1;
        int cid = e >> 7;
        int nn  = nf * 16 + (ln & 15);
        int col = (nn >> 3) * 1024 + ub0 + (nn & 7);
        int kb  = cid * 32 + (ln >> 4) * 8;
        __hip_bfloat16* dst = lu0h + (size_t)e * 8;
        #pragma unroll
        for (int j = 0; j < 8; ++j)
            dst[j] = __float2bfloat16(U0[(size_t)(kb + j) * 4096 + col]);
    }
    // ---- one-time LDS fill: W1 frags (cid 0..31)
    for (int e = tid; e < 32 * 64; e += 256) {
        int ln  = e & 63;
        int cid = e >> 6;
        int nn  = ln & 15;
        int col = (nn >> 2) * 512 + ub1 + (nn & 3);
        int kb  = cid * 32 + (ln >> 4) * 8;
        __hip_bfloat16* dst = lw1h + (size_t)e * 8;
        #pragma unroll
        for (int j = 0; j < 8; ++j)
            dst[j] = __float2bfloat16(W1[(size_t)(kb + j) * 2048 + col]);
    }
    // ---- register frags: W0 (PRE) and U1, loop-invariant
    bf16x8 bw0[4][2];
    {
        int nn0 = lane & 15;
        #pragma unroll
        for (int c = 0; c < 4; ++c)
            #pragma unroll
            for (int nf = 0; nf < 2; ++nf) {
                int nn  = nf * 16 + nn0;
                int col = (nn >> 3) * 1024 + ub0 + (nn & 7);
                int kb  = (w * 4 + c) * 32 + kgrp * 8;
                union { short s[8]; bf16x8 v; } t;
                #pragma unroll
                for (int j = 0; j < 8; ++j)
                    t.s[j] = (short)bf16bits(W0[(size_t)(kb + j) * 4096 + col]);
                bw0[c][nf] = t.v;
            }
    }
    bf16x8 bu1[4];
    {
        int nn  = lane & 15;
        int col = (nn >> 2) * 512 + ub1 + (nn & 3);
        #pragma unroll
        for (int c = 0; c < 4; ++c) {
            int kb  = (w * 4 + c) * 32 + kgrp * 8;
            union { short s[8]; bf16x8 v; } t;
            #pragma unroll
            for (int j = 0; j < 8; ++j)
                t.s[j] = (short)bf16bits(U1[(size_t)(kb + j) * 2048 + col]);
            bu1[c] = t.v;
        }
    }

    // ---- per-thread gate state: bl = tid>>3 (32 batches), qp = tid&7
    //      gates0 on qp<4 (units qp*2..+1); gates1 on qp 4..5 (units (qp-4)*2..+1)
    const int bl = tid >> 3;
    const int qp = tid & 7;
    float h0reg[2] = {0.f, 0.f}, c0reg[2] = {0.f, 0.f}, br0[8];
    float h1reg[2] = {0.f, 0.f}, c1reg[2] = {0.f, 0.f}, br1[8];
    if (qp < 4) {
        #pragma unroll
        for (int i = 0; i < 2; ++i)
            #pragma unroll
            for (int gg = 0; gg < 4; ++gg)
                br0[i * 4 + gg] = b0[gg * H0_ + ub0 + qp * 2 + i];
    }
    if (qp == 4 || qp == 5) {
        #pragma unroll
        for (int i = 0; i < 2; ++i)
            #pragma unroll
            for (int gg = 0; gg < 4; ++gg)
                br1[i * 4 + gg] = b1[gg * H1_ + ub1 + (qp - 4) * 2 + i];
    }
    __syncthreads();

    float* zp0 = (float*)(smem + LDS_ZP0);
    float* zp1 = (float*)(smem + LDS_ZP1);
    const bf16x8* lu0 = (const bf16x8*)(smem + LDS_U0);
    const bf16x8* lw1 = (const bf16x8*)(smem + LDS_W1);

    #pragma unroll 1
    for (int p = 0; p <= T_ + 1; ++p) {
        const bool doL0 = (p < T_);
        const bool doL1 = (p >= 2);          // L1 computes t1 = p-2

        f32x4 acc0[2][2];
        f32x4 acc1[2];
        #pragma unroll
        for (int m = 0; m < 2; ++m) {
            f32x4 z = {0.f, 0.f, 0.f, 0.f};
            acc0[m][0] = z; acc0[m][1] = z; acc1[m] = z;
        }

        // ---- PRE: mask prefetch + x_p*W0 (acc0) + W1*h0(p-2) (acc1); pre-wait
        bool msk0 = false, msk1 = false;
        if (doL0) msk0 = mask[(brow + bl) * T_ + p] != 0;
        if (doL1) msk1 = mask[(brow + bl) * T_ + (p - 2)] != 0;
        if (doL0) {
            const __hip_bfloat16* xa = xbf + (size_t)p * (B_ * D_);
            #pragma unroll
            for (int c = 0; c < 4; ++c) {
                const int cid = w * 4 + c;
                #pragma unroll
                for (int m = 0; m < 2; ++m) {
                    bf16x8 af = *(const bf16x8*)(xa + (size_t)(brow + m * 16 + mr) * D_ + cid * 32 + kgrp * 8);
                    acc0[m][0] = __builtin_amdgcn_mfma_f32_16x16x32_bf16(af, bw0[c][0], acc0[m][0], 0, 0, 0);
                    acc0[m][1] = __builtin_amdgcn_mfma_f32_16x16x32_bf16(af, bw0[c][1], acc0[m][1], 0, 0, 0);
                }
            }
        }
        if (doL1) {
            // h0(p-2), slot (p+2)&3 — published at phase p-2, covered by this
            // block's wait(p-1) + its fence; L2-warm (L0 read same lines at p-1).
            const __hip_bfloat16* h0p2 = h0ring + (size_t)((p + 2) & 3) * (B_ * H0_);
            #pragma unroll
            for (int c = 0; c < 8; ++c) {
                const __hip_bfloat16* src = h0p2 + w * 256 + c * 32 + kgrp * 8;
                bf16x8 bw1f = lw1[(w * 8 + c) * 64 + lane];
                #pragma unroll
                for (int m = 0; m < 2; ++m) {
                    bf16x8 af = *(const bf16x8*)(src + (size_t)(brow + m * 16 + mr) * H0_);
                    acc1[m] = __builtin_amdgcn_mfma_f32_16x16x32_bf16(af, bw1f, acc1[m], 0, 0, 0);
                }
            }
        }

        // ---- wait: wave0 polls own group's 128 block-flags, acquire fence, barrier
        if (p > 0) {
            if (tid < 64) {
                const u64* f = (const u64*)gflags + tid;
                for (;;) {
                    u64 a = ald(f);
                    if (__all(((int)a >= p) && ((int)(a >> 32) >= p))) break;
                    __builtin_amdgcn_s_sleep(1);
                }
                __builtin_amdgcn_fence(__ATOMIC_ACQUIRE, "agent");
            }
            __syncthreads();
        }

        const __hip_bfloat16* h0r = h0ring + (size_t)((p + 3) & 3) * (B_ * H0_); // h0(p-1)
        const __hip_bfloat16* h1r = h1ring + (size_t)((p + 1) & 1) * (B_ * H1_); // h1(p-3)

        // ---- h1(p-3) loads (only post-wait L1 data; issued first)
        bf16x8 h1a[4][2];
        if (doL1) {
            #pragma unroll
            for (int c = 0; c < 4; ++c) {
                const __hip_bfloat16* src = h1r + w * 128 + c * 32 + kgrp * 8;
                #pragma unroll
                for (int m = 0; m < 2; ++m)
                    h1a[c][m] = *(const bf16x8*)(src + (size_t)(brow + m * 16 + mr) * H1_);
            }
        }

        // ---- h0(p-1) pipeline: prologue 4 chunks
        bf16x8 areg[4][2];
        auto ldc = [&](int c, bf16x8* dst) {
            const __hip_bfloat16* src = h0r + w * 256 + c * 32 + kgrp * 8;
            #pragma unroll
            for (int m = 0; m < 2; ++m)
                dst[m] = *(const bf16x8*)(src + (size_t)(brow + m * 16 + mr) * H0_);
        };
        if (doL0) {
            #pragma unroll
            for (int c = 0; c < 4; ++c) ldc(c, areg[c]);
        }

        // ---- consume h1 (U1 reg frags -> acc1)
        if (doL1) {
            #pragma unroll
            for (int c = 0; c < 4; ++c) {
                #pragma unroll
                for (int m = 0; m < 2; ++m)
                    acc1[m] = __builtin_amdgcn_mfma_f32_16x16x32_bf16(h1a[c][m], bu1[c], acc1[m], 0, 0, 0);
            }
        }

        // ---- h0(p-1) loop: U0 -> acc0 (L0 only)
        if (doL0) {
            #pragma unroll
            for (int c = 0; c < 8; ++c) {
                bf16x8 cur[2];
                cur[0] = areg[c & 3][0];
                cur[1] = areg[c & 3][1];
                if (c + 4 < 8) ldc(c + 4, areg[c & 3]);
                const int wc = w * 8 + c;
                bf16x8 bu0a = lu0[(wc * 2 + 0) * 64 + lane];
                bf16x8 bu0b = lu0[(wc * 2 + 1) * 64 + lane];
                #pragma unroll
                for (int m = 0; m < 2; ++m) {
                    acc0[m][0] = __builtin_amdgcn_mfma_f32_16x16x32_bf16(cur[m], bu0a, acc0[m][0], 0, 0, 0);
                    acc0[m][1] = __builtin_amdgcn_mfma_f32_16x16x32_bf16(cur[m], bu0b, acc0[m][1], 0, 0, 0);
                }
            }
        }

        // ---- dumps to disjoint LDS, ONE sync
        if (doL0) {
            #pragma unroll
            for (int m = 0; m < 2; ++m)
                #pragma unroll
                for (int nf = 0; nf < 2; ++nf)
                    #pragma unroll
                    for (int r = 0; r < 4; ++r)
                        zp0[(w * 32 + m * 16 + kgrp * 4 + r) * ZROW0 + nf * 16 + mr] =
                            acc0[m][nf][r];
        }
        if (doL1) {
            #pragma unroll
            for (int m = 0; m < 2; ++m)
                #pragma unroll
                for (int r = 0; r < 4; ++r)
                    zp1[(w * 32 + m * 16 + kgrp * 4 + r) * ZROW1 + mr] = acc1[m][r];
        }
        __syncthreads();

        // ---- gates0 (qp<4) PARALLEL gates1 (qp 4..5), then h stores
        if (doL0 && qp < 4) {
            #pragma unroll
            for (int i = 0; i < 2; ++i) {
                const int ul = qp * 2 + i;
                float z[4];
                #pragma unroll
                for (int gg = 0; gg < 4; ++gg) {
                    float s = br0[i * 4 + gg];
                    #pragma unroll
                    for (int wv = 0; wv < 4; ++wv)
                        s += zp0[(wv * 32 + bl) * ZROW0 + gg * 8 + ul];
                    z[gg] = s;
                }
                float ig = sigmf(z[0]), fg = sigmf(z[1]);
                float gv = tanhf(z[2]), og = sigmf(z[3]);
                float cn = fg * c0reg[i] + ig * gv;
                float hn = og * tanhf(cn);
                if (msk0) { c0reg[i] = cn; h0reg[i] = hn; }
            }
            __hip_bfloat16* h0w = h0ring + (size_t)(p & 3) * (B_ * H0_);
            union { unsigned short s[2]; unsigned u; } hv;
            hv.s[0] = bf16bits(h0reg[0]);
            hv.s[1] = bf16bits(h0reg[1]);
            __hip_atomic_store((unsigned*)&h0w[(size_t)(brow + bl) * H0_ + ub0 + qp * 2], hv.u,
                               __ATOMIC_RELAXED, __HIP_MEMORY_SCOPE_AGENT);
        }
        if (doL1 && (qp == 4 || qp == 5)) {
            const int ub = (qp - 4) * 2;
            #pragma unroll
            for (int i = 0; i < 2; ++i) {
                const int ul = ub + i;
                float z[4];
                #pragma unroll
                for (int gg = 0; gg < 4; ++gg) {
                    float s = br1[i * 4 + gg];
                    #pragma unroll
                    for (int wv = 0; wv < 4; ++wv)
                        s += zp1[(wv * 32 + bl) * ZROW1 + gg * 4 + ul];
                    z[gg] = s;
                }
                float ig = sigmf(z[0]), fg = sigmf(z[1]);
                float gv = tanhf(z[2]), og = sigmf(z[3]);
                float cn = fg * c1reg[i] + ig * gv;
                float hn = og * tanhf(cn);
                if (msk1) { c1reg[i] = cn; h1reg[i] = hn; }
            }
            __hip_bfloat16* h1w = h1ring + (size_t)(p & 1) * (B_ * H1_); // slot (p-2)&1
            union { unsigned short s[2]; unsigned u; } hv;
            hv.s[0] = bf16bits(h1reg[0]);
            hv.s[1] = bf16bits(h1reg[1]);
            __hip_atomic_store((unsigned*)&h1w[(size_t)(brow + bl) * H1_ + ub1 + ub], hv.u,
                               __ATOMIC_RELAXED, __HIP_MEMORY_SCOPE_AGENT);
        }

        // ---- drain h stores (vmcnt0 in barrier), publish flag
        __syncthreads();
        if (p <= T_ && tid == 0)
            __hip_atomic_store(gflags + lb, p + 1,
                               __ATOMIC_RELAXED, __HIP_MEMORY_SCOPE_AGENT);

        // ---- out store AFTER flag (nobody reads out)
        if (doL1 && (qp == 4 || qp == 5)) {
            const int t1 = p - 2;
            float2 ov; ov.x = h1reg[0]; ov.y = h1reg[1];
            *reinterpret_cast<float2*>(&out[((size_t)(brow + bl) * T_ + t1) * H1_ + ub1 + (qp - 4) * 2]) = ov;
        }
    }
}

// ---------------------------------------------------------------------------
extern "C" void kernel_launch(void* const* d_in, const int* in_sizes, int n_in,
                              void* d_out, int out_size, void* d_ws, size_t ws_size,
                              hipStream_t stream)
{
    const float* inputs = (const float*)d_in[0];
    const float* W0     = (const float*)d_in[1];
    const float* U0     = (const float*)d_in[2];
    const float* b0     = (const float*)d_in[3];
    const float* W1     = (const float*)d_in[4];
    const float* U1     = (const float*)d_in[5];
    const float* b1     = (const float*)d_in[6];
    float* out = (float*)d_out;

    // ws (bf16 elems): xbf 16,777,216 | h0ring(4 slots) 262,144 | h1ring 65,536
    //                  | mask 32,768 B | flags 1,024 B  (~32.7 MiB)
    __hip_bfloat16* xbf    = (__hip_bfloat16*)d_ws;
    __hip_bfloat16* h0ring = xbf + 16777216;
    __hip_bfloat16* h1ring = h0ring + 262144;
    unsigned char*  mask   = (unsigned char*)(h1ring + 65536);
    int* flags = (int*)(mask + 32768);

    hipMemsetAsync(h0ring, 0, (262144 + 65536) * sizeof(__hip_bfloat16), stream);
    hipMemsetAsync(flags, 0, NWORK * sizeof(int), stream);
    mask_kernel<<<(B_ * T_) / 4, 256, 0, stream>>>(inputs, mask);
    xbf_kernel<<<(B_ * T_ * D_ / 8) / 256, 256, 0, stream>>>(inputs, xbf);

    lstm_persistent<<<dim3(NWORK), dim3(256), 0, stream>>>(
        xbf, W0, U0, W1, U1, b0, b1, mask, h0ring, h1ring, out, flags);
}

// Round 17
// 4337.437 us; speedup vs baseline: 1.2760x; 1.1396x over previous
//
#include <hip/hip_runtime.h>
#include <hip/hip_bf16.h>
#include <cstdint>
#include <cstddef>

#define B_   64
#define T_   512
#define D_   512
#define H0_  1024
#define H1_  512
#define NWORK 256    // 2 groups x 128 blocks, 1 block/CU, plain launch

typedef __attribute__((ext_vector_type(8))) short bf16x8;
typedef __attribute__((ext_vector_type(4))) float f32x4;
typedef unsigned long long u64;

// LDS: zp0 18,432B @0 | zp1 10,240B @18432  = 28,672 B (weights now in VGPRs)
#define LDS_ZP0 0
#define LDS_ZP1 18432
#define LDS_BYTES 28672
#define ZROW0 36
#define ZROW1 20

__device__ __forceinline__ float sigmf(float x) { return 1.0f / (1.0f + __expf(-x)); }
__device__ __forceinline__ unsigned short bf16bits(float x) {
    union { __hip_bfloat16 h; unsigned short s; } u; u.h = __float2bfloat16(x); return u.s;
}
__device__ __forceinline__ u64 ald(const void* p) {
    return __hip_atomic_load((const u64*)p, __ATOMIC_RELAXED, __HIP_MEMORY_SCOPE_AGENT);
}

// ---------------------------------------------------------------------------
__global__ void mask_kernel(const float* __restrict__ x, unsigned char* __restrict__ mask) {
    int row  = blockIdx.x * 4 + (threadIdx.x >> 6);
    int lane = threadIdx.x & 63;
    const float4* p = reinterpret_cast<const float4*>(x + (size_t)row * D_) + lane * 2;
    float4 a = p[0], b = p[1];
    bool nz = (a.x != 0.f) | (a.y != 0.f) | (a.z != 0.f) | (a.w != 0.f)
            | (b.x != 0.f) | (b.y != 0.f) | (b.z != 0.f) | (b.w != 0.f);
    int m = __any(nz);
    if (lane == 0) mask[row] = m ? 1 : 0;
}

__global__ void xbf_kernel(const float* __restrict__ in, __hip_bfloat16* __restrict__ xbf) {
    int i  = blockIdx.x * 256 + threadIdx.x;
    int d8 = i & 63;
    int row = i >> 6;
    int b = row >> 9, t = row & 511;
    const float* src = in + (size_t)row * D_ + d8 * 8;
    __hip_bfloat16 o[8];
    #pragma unroll
    for (int j = 0; j < 8; ++j) o[j] = __float2bfloat16(src[j]);
    *reinterpret_cast<bf16x8*>(xbf + ((size_t)t * B_ + b) * D_ + d8 * 8) =
        *reinterpret_cast<bf16x8*>(o);
}

// ---------------------------------------------------------------------------
// R13 structure, weights ALL in VGPRs (U0 16 frags + W1 8 frags + W0 8 + U1 4
// per wave = 144 frag VGPRs; statically indexed, fully unrolled loops).
// Group g = bid>>7 owns batches [g*32,+32); block lb = bid&127 owns
// 8 L0-units + 4 L1-units. Phase p: PRE = mask + x_p*W0 (reg frags);
// wait = wave0 polls 128 block-flags + acquire fence (L2 inv) + barrier;
// POST: h1(p-2) loads -> U1; h0(p-1) 4-deep pipeline -> U0 (z0) + W1 (z1),
// shared A-frags, pure reg/MFMA (no LDS on critical path);
// zp dumps -> sync -> gates -> h stores (sc0sc1) -> sync -> flag -> out.
// ---------------------------------------------------------------------------
__global__ __launch_bounds__(256, 1)
void lstm_persistent(const __hip_bfloat16* __restrict__ xbf,
    const float* __restrict__ W0, const float* __restrict__ U0,
    const float* __restrict__ W1, const float* __restrict__ U1,
    const float* __restrict__ b0, const float* __restrict__ b1,
    const unsigned char* __restrict__ mask,
    __hip_bfloat16* h0ring, __hip_bfloat16* h1ring, float* __restrict__ out,
    int* flags)
{
    __shared__ __align__(16) unsigned char smem[LDS_BYTES];
    const int bid = blockIdx.x;
    const int g   = bid >> 7;          // batch group (0/1)
    const int lb  = bid & 127;         // block within group
    const int tid = threadIdx.x;
    const int w = tid >> 6, lane = tid & 63;
    const int mr = lane & 15, kgrp = lane >> 4;
    const int ub0 = lb * 8, ub1 = lb * 4;
    const int brow = g * 32;           // batch row base
    int* gflags = flags + g * 128;

    // ---- register frags (loop-invariant, statically indexed everywhere)
    // W0: PRE x-chunks (cid = w*4+c), 2 nf           -> 32 VGPR
    // U0: h0-chunks (cid = w*8+c), 2 nf              -> 64 VGPR
    // W1: h0-chunks (cid = w*8+c), 1 nf              -> 32 VGPR
    // U1: h1-chunks (cid = w*4+c), 1 nf              -> 16 VGPR
    bf16x8 bw0[4][2], bu0r[8][2], bw1r[8], bu1[4];
    {
        const int nn0 = lane & 15;
        #pragma unroll
        for (int c = 0; c < 4; ++c)
            #pragma unroll
            for (int nf = 0; nf < 2; ++nf) {
                int nn  = nf * 16 + nn0;
                int col = (nn >> 3) * 1024 + ub0 + (nn & 7);
                int kb  = (w * 4 + c) * 32 + kgrp * 8;
                union { short s[8]; bf16x8 v; } t;
                #pragma unroll
                for (int j = 0; j < 8; ++j)
                    t.s[j] = (short)bf16bits(W0[(size_t)(kb + j) * 4096 + col]);
                bw0[c][nf] = t.v;
            }
        #pragma unroll
        for (int c = 0; c < 8; ++c)
            #pragma unroll
            for (int nf = 0; nf < 2; ++nf) {
                int nn  = nf * 16 + nn0;
                int col = (nn >> 3) * 1024 + ub0 + (nn & 7);
                int kb  = (w * 8 + c) * 32 + kgrp * 8;
                union { short s[8]; bf16x8 v; } t;
                #pragma unroll
                for (int j = 0; j < 8; ++j)
                    t.s[j] = (short)bf16bits(U0[(size_t)(kb + j) * 4096 + col]);
                bu0r[c][nf] = t.v;
            }
        {
            int col = (nn0 >> 2) * 512 + ub1 + (nn0 & 3);
            #pragma unroll
            for (int c = 0; c < 8; ++c) {
                int kb  = (w * 8 + c) * 32 + kgrp * 8;
                union { short s[8]; bf16x8 v; } t;
                #pragma unroll
                for (int j = 0; j < 8; ++j)
                    t.s[j] = (short)bf16bits(W1[(size_t)(kb + j) * 2048 + col]);
                bw1r[c] = t.v;
            }
            #pragma unroll
            for (int c = 0; c < 4; ++c) {
                int kb  = (w * 4 + c) * 32 + kgrp * 8;
                union { short s[8]; bf16x8 v; } t;
                #pragma unroll
                for (int j = 0; j < 8; ++j)
                    t.s[j] = (short)bf16bits(U1[(size_t)(kb + j) * 2048 + col]);
                bu1[c] = t.v;
            }
        }
    }

    // ---- per-thread gate state: bl = tid>>3 (32 batches), qp = tid&7
    const int bl = tid >> 3;
    const int qp = tid & 7;
    float h0reg[2] = {0.f, 0.f}, c0reg[2] = {0.f, 0.f}, br0[8];
    float h1reg[2] = {0.f, 0.f}, c1reg[2] = {0.f, 0.f}, br1[8];
    if (qp < 4) {
        #pragma unroll
        for (int i = 0; i < 2; ++i)
            #pragma unroll
            for (int gg = 0; gg < 4; ++gg)
                br0[i * 4 + gg] = b0[gg * H0_ + ub0 + qp * 2 + i];
    }
    if (qp < 2) {
        #pragma unroll
        for (int i = 0; i < 2; ++i)
            #pragma unroll
            for (int gg = 0; gg < 4; ++gg)
                br1[i * 4 + gg] = b1[gg * H1_ + ub1 + qp * 2 + i];
    }
    __syncthreads();

    float* zp0 = (float*)(smem + LDS_ZP0);
    float* zp1 = (float*)(smem + LDS_ZP1);

    #pragma unroll 1
    for (int p = 0; p <= T_; ++p) {
        const bool doL0 = (p < T_);
        const bool doL1 = (p >= 1);

        f32x4 acc0[2][2];
        f32x4 acc1[2];
        #pragma unroll
        for (int m = 0; m < 2; ++m) {
            f32x4 z = {0.f, 0.f, 0.f, 0.f};
            acc0[m][0] = z; acc0[m][1] = z; acc1[m] = z;
        }

        // ---- PRE: mask prefetch + z0 x-part (W0 reg frags; pre-wait)
        bool msk0 = false, msk1 = false;
        if (doL0) msk0 = mask[(brow + bl) * T_ + p] != 0;
        if (doL1) msk1 = mask[(brow + bl) * T_ + (p - 1)] != 0;
        if (doL0) {
            const __hip_bfloat16* xa = xbf + (size_t)p * (B_ * D_);
            #pragma unroll
            for (int c = 0; c < 4; ++c) {
                const int cid = w * 4 + c;
                #pragma unroll
                for (int m = 0; m < 2; ++m) {
                    bf16x8 af = *(const bf16x8*)(xa + (size_t)(brow + m * 16 + mr) * D_ + cid * 32 + kgrp * 8);
                    acc0[m][0] = __builtin_amdgcn_mfma_f32_16x16x32_bf16(af, bw0[c][0], acc0[m][0], 0, 0, 0);
                    acc0[m][1] = __builtin_amdgcn_mfma_f32_16x16x32_bf16(af, bw0[c][1], acc0[m][1], 0, 0, 0);
                }
            }
        }

        // ---- wait: wave0 polls own group's 128 block-flags, acquire fence, barrier
        if (p > 0) {
            if (tid < 64) {
                const u64* f = (const u64*)gflags + tid;
                for (;;) {
                    u64 a = ald(f);
                    if (__all(((int)a >= p) && ((int)(a >> 32) >= p))) break;
                    __builtin_amdgcn_s_sleep(1);
                }
                __builtin_amdgcn_fence(__ATOMIC_ACQUIRE, "agent");
            }
            __syncthreads();
        }

        const __hip_bfloat16* h0r = h0ring + (size_t)((p + 1) & 1) * (B_ * H0_); // h0(p-1)
        const __hip_bfloat16* h1r = h1ring + (size_t)(p & 1) * (B_ * H1_);       // h1(p-2)

        // ---- h1 loads (plain cached, L2-amplified; issued first)
        bf16x8 h1a[4][2];
        if (doL1) {
            #pragma unroll
            for (int c = 0; c < 4; ++c) {
                const __hip_bfloat16* src = h1r + w * 128 + c * 32 + kgrp * 8;
                #pragma unroll
                for (int m = 0; m < 2; ++m)
                    h1a[c][m] = *(const bf16x8*)(src + (size_t)(brow + m * 16 + mr) * H1_);
            }
        }

        // ---- h0 pipeline: prologue 4 chunks (plain cached loads)
        bf16x8 areg[4][2];
        auto ldc = [&](int c, bf16x8* dst) {
            const __hip_bfloat16* src = h0r + w * 256 + c * 32 + kgrp * 8;
            #pragma unroll
            for (int m = 0; m < 2; ++m)
                dst[m] = *(const bf16x8*)(src + (size_t)(brow + m * 16 + mr) * H0_);
        };
        #pragma unroll
        for (int c = 0; c < 4; ++c) ldc(c, areg[c]);

        // ---- consume h1 (U1 reg frags -> z1)
        if (doL1) {
            #pragma unroll
            for (int c = 0; c < 4; ++c) {
                #pragma unroll
                for (int m = 0; m < 2; ++m)
                    acc1[m] = __builtin_amdgcn_mfma_f32_16x16x32_bf16(h1a[c][m], bu1[c], acc1[m], 0, 0, 0);
            }
        }

        // ---- h0 loop: shared A-frags feed U0 (z0) and W1 (z1), all reg frags
        #pragma unroll
        for (int c = 0; c < 8; ++c) {
            bf16x8 cur[2];
            cur[0] = areg[c & 3][0];
            cur[1] = areg[c & 3][1];
            if (c + 4 < 8) ldc(c + 4, areg[c & 3]);
            #pragma unroll
            for (int m = 0; m < 2; ++m) {
                if (doL0) {
                    acc0[m][0] = __builtin_amdgcn_mfma_f32_16x16x32_bf16(cur[m], bu0r[c][0], acc0[m][0], 0, 0, 0);
                    acc0[m][1] = __builtin_amdgcn_mfma_f32_16x16x32_bf16(cur[m], bu0r[c][1], acc0[m][1], 0, 0, 0);
                }
                if (doL1)
                    acc1[m] = __builtin_amdgcn_mfma_f32_16x16x32_bf16(cur[m], bw1r[c], acc1[m], 0, 0, 0);
            }
        }

        // ---- dumps to disjoint LDS, ONE sync
        if (doL0) {
            #pragma unroll
            for (int m = 0; m < 2; ++m)
                #pragma unroll
                for (int nf = 0; nf < 2; ++nf)
                    #pragma unroll
                    for (int r = 0; r < 4; ++r)
                        zp0[(w * 32 + m * 16 + kgrp * 4 + r) * ZROW0 + nf * 16 + mr] =
                            acc0[m][nf][r];
        }
        if (doL1) {
            #pragma unroll
            for (int m = 0; m < 2; ++m)
                #pragma unroll
                for (int r = 0; r < 4; ++r)
                    zp1[(w * 32 + m * 16 + kgrp * 4 + r) * ZROW1 + mr] = acc1[m][r];
        }
        __syncthreads();

        // ---- gates0 (qp<4) and gates1 (qp<2), then h stores
        if (doL0 && qp < 4) {
            #pragma unroll
            for (int i = 0; i < 2; ++i) {
                const int ul = qp * 2 + i;
                float z[4];
                #pragma unroll
                for (int gg = 0; gg < 4; ++gg) {
                    float s = br0[i * 4 + gg];
                    #pragma unroll
                    for (int wv = 0; wv < 4; ++wv)
                        s += zp0[(wv * 32 + bl) * ZROW0 + gg * 8 + ul];
                    z[gg] = s;
                }
                float ig = sigmf(z[0]), fg = sigmf(z[1]);
                float gv = tanhf(z[2]), og = sigmf(z[3]);
                float cn = fg * c0reg[i] + ig * gv;
                float hn = og * tanhf(cn);
                if (msk0) { c0reg[i] = cn; h0reg[i] = hn; }
            }
            __hip_bfloat16* h0w = h0ring + (size_t)(p & 1) * (B_ * H0_);
            union { unsigned short s[2]; unsigned u; } hv;
            hv.s[0] = bf16bits(h0reg[0]);
            hv.s[1] = bf16bits(h0reg[1]);
            __hip_atomic_store((unsigned*)&h0w[(size_t)(brow + bl) * H0_ + ub0 + qp * 2], hv.u,
                               __ATOMIC_RELAXED, __HIP_MEMORY_SCOPE_AGENT);
        }
        if (doL1 && qp < 2) {
            #pragma unroll
            for (int i = 0; i < 2; ++i) {
                const int ul = qp * 2 + i;
                float z[4];
                #pragma unroll
                for (int gg = 0; gg < 4; ++gg) {
                    float s = br1[i * 4 + gg];
                    #pragma unroll
                    for (int wv = 0; wv < 4; ++wv)
                        s += zp1[(wv * 32 + bl) * ZROW1 + gg * 4 + ul];
                    z[gg] = s;
                }
                float ig = sigmf(z[0]), fg = sigmf(z[1]);
                float gv = tanhf(z[2]), og = sigmf(z[3]);
                float cn = fg * c1reg[i] + ig * gv;
                float hn = og * tanhf(cn);
                if (msk1) { c1reg[i] = cn; h1reg[i] = hn; }
            }
            __hip_bfloat16* h1w = h1ring + (size_t)((p + 1) & 1) * (B_ * H1_); // slot (p-1)&1
            union { unsigned short s[2]; unsigned u; } hv;
            hv.s[0] = bf16bits(h1reg[0]);
            hv.s[1] = bf16bits(h1reg[1]);
            __hip_atomic_store((unsigned*)&h1w[(size_t)(brow + bl) * H1_ + ub1 + qp * 2], hv.u,
                               __ATOMIC_RELAXED, __HIP_MEMORY_SCOPE_AGENT);
        }

        // ---- drain h stores (per-wave vmcnt0 inside barrier), publish flag
        __syncthreads();
        if (p < T_ && tid == 0)
            __hip_atomic_store(gflags + lb, p + 1,
                               __ATOMIC_RELAXED, __HIP_MEMORY_SCOPE_AGENT);

        // ---- out store AFTER flag publish (nobody reads out)
        if (doL1 && qp < 2) {
            const int t1 = p - 1;
            float2 ov; ov.x = h1reg[0]; ov.y = h1reg[1];
            *reinterpret_cast<float2*>(&out[((size_t)(brow + bl) * T_ + t1) * H1_ + ub1 + qp * 2]) = ov;
        }
    }
}

// ---------------------------------------------------------------------------
extern "C" void kernel_launch(void* const* d_in, const int* in_sizes, int n_in,
                              void* d_out, int out_size, void* d_ws, size_t ws_size,
                              hipStream_t stream)
{
    const float* inputs = (const float*)d_in[0];
    const float* W0     = (const float*)d_in[1];
    const float* U0     = (const float*)d_in[2];
    const float* b0     = (const float*)d_in[3];
    const float* W1     = (const float*)d_in[4];
    const float* U1     = (const float*)d_in[5];
    const float* b1     = (const float*)d_in[6];
    float* out = (float*)d_out;

    // ws (bf16 elems): xbf 16,777,216 | h0ring 131,072 | h1ring 65,536
    //                  | mask 32,768 B | flags 1,024 B  (~32.4 MiB)
    __hip_bfloat16* xbf    = (__hip_bfloat16*)d_ws;
    __hip_bfloat16* h0ring = xbf + 16777216;
    __hip_bfloat16* h1ring = h0ring + 131072;
    unsigned char*  mask   = (unsigned char*)(h1ring + 65536);
    int* flags = (int*)(mask + 32768);

    hipMemsetAsync(h0ring, 0, (131072 + 65536) * sizeof(__hip_bfloat16), stream);
    hipMemsetAsync(flags, 0, NWORK * sizeof(int), stream);
    mask_kernel<<<(B_ * T_) / 4, 256, 0, stream>>>(inputs, mask);
    xbf_kernel<<<(B_ * T_ * D_ / 8) / 256, 256, 0, stream>>>(inputs, xbf);

    lstm_persistent<<<dim3(NWORK), dim3(256), 0, stream>>>(
        xbf, W0, U0, W1, U1, b0, b1, mask, h0ring, h1ring, out, flags);
}

// Round 18
// 3011.708 us; speedup vs baseline: 1.8376x; 1.4402x over previous
//
#include <hip/hip_runtime.h>
#include <hip/hip_bf16.h>
#include <cstdint>
#include <cstddef>

#define B_   64
#define T_   512
#define D_   512
#define H0_  1024
#define H1_  512
#define NGRP 4
#define BPG  64
#define NWORK 256    // 4 groups x 64 blocks, 1 block/CU, plain launch

typedef __attribute__((ext_vector_type(8))) short bf16x8;
typedef __attribute__((ext_vector_type(4))) float f32x4;
typedef unsigned long long u64;

// LDS: zp0 (64 rows x 68 f) 17,408 B @0 | zp1 (64 x 36 f) 9,216 B @17408
#define LDS_ZP0 0
#define LDS_ZP1 17408
#define LDS_BYTES 26624
#define ZROW0 68
#define ZROW1 36

__device__ __forceinline__ float sigmf(float x) { return 1.0f / (1.0f + __expf(-x)); }
__device__ __forceinline__ unsigned short bf16bits(float x) {
    union { __hip_bfloat16 h; unsigned short s; } u; u.h = __float2bfloat16(x); return u.s;
}

// ---------------------------------------------------------------------------
__global__ void mask_kernel(const float* __restrict__ x, unsigned char* __restrict__ mask) {
    int row  = blockIdx.x * 4 + (threadIdx.x >> 6);
    int lane = threadIdx.x & 63;
    const float4* p = reinterpret_cast<const float4*>(x + (size_t)row * D_) + lane * 2;
    float4 a = p[0], b = p[1];
    bool nz = (a.x != 0.f) | (a.y != 0.f) | (a.z != 0.f) | (a.w != 0.f)
            | (b.x != 0.f) | (b.y != 0.f) | (b.z != 0.f) | (b.w != 0.f);
    int m = __any(nz);
    if (lane == 0) mask[row] = m ? 1 : 0;
}

__global__ void xbf_kernel(const float* __restrict__ in, __hip_bfloat16* __restrict__ xbf) {
    int i  = blockIdx.x * 256 + threadIdx.x;
    int d8 = i & 63;
    int row = i >> 6;
    int b = row >> 9, t = row & 511;
    const float* src = in + (size_t)row * D_ + d8 * 8;
    __hip_bfloat16 o[8];
    #pragma unroll
    for (int j = 0; j < 8; ++j) o[j] = __float2bfloat16(src[j]);
    *reinterpret_cast<bf16x8*>(xbf + ((size_t)t * B_ + b) * D_ + d8 * 8) =
        *reinterpret_cast<bf16x8*>(o);
}

// ---------------------------------------------------------------------------
// 4 independent batch-group chains (16 batches each), 64 blocks/group.
// Block owns 16 L0-units + 8 L1-units, M=16 (single m-tile).
// Protocol identical R13: PRE (mask + x_p*W0, reg frags) overlaps the wait;
// wave0 polls 64 int flags (1/lane) + acquire fence + barrier;
// POST: h1(p-2) -> U1; h0(p-1) 4-deep pipeline -> U0 (z0, 4 frags) +
// W1 (z1, 2 frags), shared A-frags, all-VGPR weights;
// zp dumps -> sync -> gates0 (waves 0-1) PARALLEL gates1 (wave 2) ->
// h stores (sc0sc1) -> sync -> flag -> out store.
// ---------------------------------------------------------------------------
__global__ __launch_bounds__(256, 1)
void lstm_persistent(const __hip_bfloat16* __restrict__ xbf,
    const float* __restrict__ W0, const float* __restrict__ U0,
    const float* __restrict__ W1, const float* __restrict__ U1,
    const float* __restrict__ b0, const float* __restrict__ b1,
    const unsigned char* __restrict__ mask,
    __hip_bfloat16* h0ring, __hip_bfloat16* h1ring, float* __restrict__ out,
    int* flags)
{
    __shared__ __align__(16) unsigned char smem[LDS_BYTES];
    const int bid = blockIdx.x;
    const int g   = bid >> 6;          // group (0..3)
    const int lb  = bid & 63;          // block within group
    const int tid = threadIdx.x;
    const int w = tid >> 6, lane = tid & 63;
    const int mr = lane & 15, kgrp = lane >> 4;
    const int ub0 = lb * 16, ub1 = lb * 8;
    const int brow = g * 16;           // batch row base
    int* gflags = flags + g * BPG;

    // ---- register frags (loop-invariant, statically indexed)
    // W0: 4 x-chunks x 4 nf | U0: 8 h0-chunks x 4 nf | W1: 8 x 2 | U1: 4 x 2
    bf16x8 bw0[4][4], bu0r[8][4], bw1r[8][2], bu1[4][2];
    {
        const int nn0 = lane & 15;
        #pragma unroll
        for (int c = 0; c < 4; ++c)
            #pragma unroll
            for (int nf = 0; nf < 4; ++nf) {
                int col = nf * 1024 + ub0 + nn0;              // gate=nf, unit=nn0
                int kb  = (w * 4 + c) * 32 + kgrp * 8;
                union { short s[8]; bf16x8 v; } t;
                #pragma unroll
                for (int j = 0; j < 8; ++j)
                    t.s[j] = (short)bf16bits(W0[(size_t)(kb + j) * 4096 + col]);
                bw0[c][nf] = t.v;
            }
        #pragma unroll
        for (int c = 0; c < 8; ++c)
            #pragma unroll
            for (int nf = 0; nf < 4; ++nf) {
                int col = nf * 1024 + ub0 + nn0;
                int kb  = (w * 8 + c) * 32 + kgrp * 8;
                union { short s[8]; bf16x8 v; } t;
                #pragma unroll
                for (int j = 0; j < 8; ++j)
                    t.s[j] = (short)bf16bits(U0[(size_t)(kb + j) * 4096 + col]);
                bu0r[c][nf] = t.v;
            }
        #pragma unroll
        for (int c = 0; c < 8; ++c)
            #pragma unroll
            for (int nf = 0; nf < 2; ++nf) {
                int nn  = nf * 16 + nn0;                      // gate=nn>>3, unit=nn&7
                int col = (nn >> 3) * 512 + ub1 + (nn & 7);
                int kb  = (w * 8 + c) * 32 + kgrp * 8;
                union { short s[8]; bf16x8 v; } t;
                #pragma unroll
                for (int j = 0; j < 8; ++j)
                    t.s[j] = (short)bf16bits(W1[(size_t)(kb + j) * 2048 + col]);
                bw1r[c][nf] = t.v;
            }
        #pragma unroll
        for (int c = 0; c < 4; ++c)
            #pragma unroll
            for (int nf = 0; nf < 2; ++nf) {
                int nn  = nf * 16 + nn0;
                int col = (nn >> 3) * 512 + ub1 + (nn & 7);
                int kb  = (w * 4 + c) * 32 + kgrp * 8;
                union { short s[8]; bf16x8 v; } t;
                #pragma unroll
                for (int j = 0; j < 8; ++j)
                    t.s[j] = (short)bf16bits(U1[(size_t)(kb + j) * 2048 + col]);
                bu1[c][nf] = t.v;
            }
    }

    // ---- gate-thread mappings (disjoint waves -> parallel gate phases)
    // gates0: tid<128  -> b = tid>>3,        up = (tid&7)*2   (16 units)
    // gates1: tid in [128,192) -> b=(tid-128)>>2, up=((tid-128)&3)*2 (8 units)
    const bool g0t = (tid < 128);
    const bool g1t = (tid >= 128 && tid < 192);
    const int b0i = tid >> 3;
    const int up0 = (tid & 7) * 2;
    const int b1i = (tid - 128) >> 2;
    const int up1 = ((tid - 128) & 3) * 2;

    float h0reg[2] = {0.f, 0.f}, c0reg[2] = {0.f, 0.f}, br0[8];
    float h1reg[2] = {0.f, 0.f}, c1reg[2] = {0.f, 0.f}, br1[8];
    if (g0t) {
        #pragma unroll
        for (int gg = 0; gg < 4; ++gg) {
            br0[gg]     = b0[gg * H0_ + ub0 + up0];
            br0[4 + gg] = b0[gg * H0_ + ub0 + up0 + 1];
        }
    }
    if (g1t) {
        #pragma unroll
        for (int gg = 0; gg < 4; ++gg) {
            br1[gg]     = b1[gg * H1_ + ub1 + up1];
            br1[4 + gg] = b1[gg * H1_ + ub1 + up1 + 1];
        }
    }
    __syncthreads();

    float* zp0 = (float*)(smem + LDS_ZP0);
    float* zp1 = (float*)(smem + LDS_ZP1);

    #pragma unroll 1
    for (int p = 0; p <= T_; ++p) {
        const bool doL0 = (p < T_);
        const bool doL1 = (p >= 1);

        f32x4 acc0[4];
        f32x4 acc1[2];
        #pragma unroll
        for (int nf = 0; nf < 4; ++nf) { f32x4 z = {0.f,0.f,0.f,0.f}; acc0[nf] = z; }
        #pragma unroll
        for (int nf = 0; nf < 2; ++nf) { f32x4 z = {0.f,0.f,0.f,0.f}; acc1[nf] = z; }

        // ---- PRE: mask prefetch + z0 x-part (W0 reg frags; pre-wait)
        bool msk0 = false, msk1 = false;
        if (doL0 && g0t) msk0 = mask[(brow + b0i) * T_ + p] != 0;
        if (doL1 && g1t) msk1 = mask[(brow + b1i) * T_ + (p - 1)] != 0;
        if (doL0) {
            const __hip_bfloat16* xa = xbf + (size_t)p * (B_ * D_)
                                     + (size_t)(brow + mr) * D_ + kgrp * 8;
            #pragma unroll
            for (int c = 0; c < 4; ++c) {
                bf16x8 af = *(const bf16x8*)(xa + (w * 4 + c) * 32);
                #pragma unroll
                for (int nf = 0; nf < 4; ++nf)
                    acc0[nf] = __builtin_amdgcn_mfma_f32_16x16x32_bf16(af, bw0[c][nf], acc0[nf], 0, 0, 0);
            }
        }

        // ---- wait: wave0 polls own group's 64 int flags (1/lane), fence, barrier
        if (p > 0) {
            if (tid < 64) {
                for (;;) {
                    int a = __hip_atomic_load(gflags + tid, __ATOMIC_RELAXED, __HIP_MEMORY_SCOPE_AGENT);
                    if (__all(a >= p)) break;
                    __builtin_amdgcn_s_sleep(1);
                }
                __builtin_amdgcn_fence(__ATOMIC_ACQUIRE, "agent");
            }
            __syncthreads();
        }

        const __hip_bfloat16* h0r = h0ring + (size_t)((p + 1) & 1) * (B_ * H0_); // h0(p-1)
        const __hip_bfloat16* h1r = h1ring + (size_t)(p & 1) * (B_ * H1_);       // h1(p-2)

        // ---- h1 loads (plain cached; issued first)
        bf16x8 h1a[4];
        if (doL1) {
            const __hip_bfloat16* src = h1r + (size_t)(brow + mr) * H1_ + kgrp * 8;
            #pragma unroll
            for (int c = 0; c < 4; ++c)
                h1a[c] = *(const bf16x8*)(src + (w * 4 + c) * 32);
        }

        // ---- h0 pipeline: prologue 4 chunks
        const __hip_bfloat16* h0s = h0r + (size_t)(brow + mr) * H0_ + kgrp * 8;
        bf16x8 areg[4];
        #pragma unroll
        for (int c = 0; c < 4; ++c)
            areg[c] = *(const bf16x8*)(h0s + (w * 8 + c) * 32);

        // ---- consume h1 (U1 reg frags -> z1)
        if (doL1) {
            #pragma unroll
            for (int c = 0; c < 4; ++c)
                #pragma unroll
                for (int nf = 0; nf < 2; ++nf)
                    acc1[nf] = __builtin_amdgcn_mfma_f32_16x16x32_bf16(h1a[c], bu1[c][nf], acc1[nf], 0, 0, 0);
        }

        // ---- h0 loop: shared A-frags feed U0 (z0, 4 nf) and W1 (z1, 2 nf)
        #pragma unroll
        for (int c = 0; c < 8; ++c) {
            bf16x8 cur = areg[c & 3];
            if (c + 4 < 8) areg[c & 3] = *(const bf16x8*)(h0s + (w * 8 + c + 4) * 32);
            if (doL0) {
                #pragma unroll
                for (int nf = 0; nf < 4; ++nf)
                    acc0[nf] = __builtin_amdgcn_mfma_f32_16x16x32_bf16(cur, bu0r[c][nf], acc0[nf], 0, 0, 0);
            }
            if (doL1) {
                #pragma unroll
                for (int nf = 0; nf < 2; ++nf)
                    acc1[nf] = __builtin_amdgcn_mfma_f32_16x16x32_bf16(cur, bw1r[c][nf], acc1[nf], 0, 0, 0);
            }
        }

        // ---- dumps to disjoint LDS, ONE sync
        if (doL0) {
            #pragma unroll
            for (int nf = 0; nf < 4; ++nf)
                #pragma unroll
                for (int r = 0; r < 4; ++r)
                    zp0[(w * 16 + kgrp * 4 + r) * ZROW0 + nf * 16 + mr] = acc0[nf][r];
        }
        if (doL1) {
            #pragma unroll
            for (int nf = 0; nf < 2; ++nf)
                #pragma unroll
                for (int r = 0; r < 4; ++r)
                    zp1[(w * 16 + kgrp * 4 + r) * ZROW1 + nf * 16 + mr] = acc1[nf][r];
        }
        __syncthreads();

        // ---- gates0 (waves 0-1) PARALLEL gates1 (wave 2), then h stores
        if (doL0 && g0t) {
            float z[2][4];
            #pragma unroll
            for (int gg = 0; gg < 4; ++gg) {
                float sx = 0.f, sy = 0.f;
                #pragma unroll
                for (int wv = 0; wv < 4; ++wv) {
                    float2 s = *(const float2*)&zp0[(wv * 16 + b0i) * ZROW0 + gg * 16 + up0];
                    sx += s.x; sy += s.y;
                }
                z[0][gg] = sx + br0[gg];
                z[1][gg] = sy + br0[4 + gg];
            }
            #pragma unroll
            for (int i = 0; i < 2; ++i) {
                float ig = sigmf(z[i][0]), fg = sigmf(z[i][1]);
                float gv = tanhf(z[i][2]), og = sigmf(z[i][3]);
                float cn = fg * c0reg[i] + ig * gv;
                float hn = og * tanhf(cn);
                if (msk0) { c0reg[i] = cn; h0reg[i] = hn; }
            }
            __hip_bfloat16* h0w = h0ring + (size_t)(p & 1) * (B_ * H0_);
            union { unsigned short s[2]; unsigned u; } hv;
            hv.s[0] = bf16bits(h0reg[0]);
            hv.s[1] = bf16bits(h0reg[1]);
            __hip_atomic_store((unsigned*)&h0w[(size_t)(brow + b0i) * H0_ + ub0 + up0], hv.u,
                               __ATOMIC_RELAXED, __HIP_MEMORY_SCOPE_AGENT);
        }
        if (doL1 && g1t) {
            float z[2][4];
            #pragma unroll
            for (int gg = 0; gg < 4; ++gg) {
                float sx = 0.f, sy = 0.f;
                #pragma unroll
                for (int wv = 0; wv < 4; ++wv) {
                    float2 s = *(const float2*)&zp1[(wv * 16 + b1i) * ZROW1 + gg * 8 + up1];
                    sx += s.x; sy += s.y;
                }
                z[0][gg] = sx + br1[gg];
                z[1][gg] = sy + br1[4 + gg];
            }
            #pragma unroll
            for (int i = 0; i < 2; ++i) {
                float ig = sigmf(z[i][0]), fg = sigmf(z[i][1]);
                float gv = tanhf(z[i][2]), og = sigmf(z[i][3]);
                float cn = fg * c1reg[i] + ig * gv;
                float hn = og * tanhf(cn);
                if (msk1) { c1reg[i] = cn; h1reg[i] = hn; }
            }
            __hip_bfloat16* h1w = h1ring + (size_t)((p + 1) & 1) * (B_ * H1_); // slot (p-1)&1
            union { unsigned short s[2]; unsigned u; } hv;
            hv.s[0] = bf16bits(h1reg[0]);
            hv.s[1] = bf16bits(h1reg[1]);
            __hip_atomic_store((unsigned*)&h1w[(size_t)(brow + b1i) * H1_ + ub1 + up1], hv.u,
                               __ATOMIC_RELAXED, __HIP_MEMORY_SCOPE_AGENT);
        }

        // ---- drain h stores (vmcnt0 inside barrier), publish flag
        __syncthreads();
        if (p < T_ && tid == 0)
            __hip_atomic_store(gflags + lb, p + 1,
                               __ATOMIC_RELAXED, __HIP_MEMORY_SCOPE_AGENT);

        // ---- out store AFTER flag publish (nobody reads out)
        if (doL1 && g1t) {
            const int t1 = p - 1;
            float2 ov; ov.x = h1reg[0]; ov.y = h1reg[1];
            *reinterpret_cast<float2*>(&out[((size_t)(brow + b1i) * T_ + t1) * H1_ + ub1 + up1]) = ov;
        }
    }
}

// ---------------------------------------------------------------------------
extern "C" void kernel_launch(void* const* d_in, const int* in_sizes, int n_in,
                              void* d_out, int out_size, void* d_ws, size_t ws_size,
                              hipStream_t stream)
{
    const float* inputs = (const float*)d_in[0];
    const float* W0     = (const float*)d_in[1];
    const float* U0     = (const float*)d_in[2];
    const float* b0     = (const float*)d_in[3];
    const float* W1     = (const float*)d_in[4];
    const float* U1     = (const float*)d_in[5];
    const float* b1     = (const float*)d_in[6];
    float* out = (float*)d_out;

    // ws (bf16 elems): xbf 16,777,216 | h0ring 131,072 | h1ring 65,536
    //                  | mask 32,768 B | flags 1,024 B  (~32.4 MiB)
    __hip_bfloat16* xbf    = (__hip_bfloat16*)d_ws;
    __hip_bfloat16* h0ring = xbf + 16777216;
    __hip_bfloat16* h1ring = h0ring + 131072;
    unsigned char*  mask   = (unsigned char*)(h1ring + 65536);
    int* flags = (int*)(mask + 32768);

    hipMemsetAsync(h0ring, 0, (131072 + 65536) * sizeof(__hip_bfloat16), stream);
    hipMemsetAsync(flags, 0, NWORK * sizeof(int), stream);
    mask_kernel<<<(B_ * T_) / 4, 256, 0, stream>>>(inputs, mask);
    xbf_kernel<<<(B_ * T_ * D_ / 8) / 256, 256, 0, stream>>>(inputs, xbf);

    lstm_persistent<<<dim3(NWORK), dim3(256), 0, stream>>>(
        xbf, W0, U0, W1, U1, b0, b1, mask, h0ring, h1ring, out, flags);
}